// Round 1
// baseline (2380.096 us; speedup 1.0000x reference)
//
#include <hip/hip_runtime.h>
#include <math.h>

#define EMB 64
static constexpr float INV_SQRT_DK = 0.17677669529663687f; // 1/sqrt(32)

// ---------------- proj = e @ W_Q (wave per row, W in LDS) ----------------
__global__ void proj_kernel(const float* __restrict__ e, const float* __restrict__ W,
                            float* __restrict__ proj, int n) {
    __shared__ float Wl[64 * 64];
    int t = threadIdx.x;
    for (int i = t; i < 64 * 64; i += blockDim.x) Wl[i] = W[i];
    __syncthreads();
    int lane = t & 63;
    int wavesPerBlock = blockDim.x >> 6;
    int wid = blockIdx.x * wavesPerBlock + (t >> 6);
    int nw = gridDim.x * wavesPerBlock;
    for (int r = wid; r < n; r += nw) {
        float x = e[(size_t)r * EMB + lane];
        float acc = 0.f;
#pragma unroll
        for (int k = 0; k < 64; ++k) {
            float ek = __shfl(x, k, 64);
            acc += ek * Wl[k * 64 + lane];
        }
        proj[(size_t)r * EMB + lane] = acc;
    }
}

// ------------- edge scores: ex = exp(score), ssum = segment sum -------------
__global__ void edge_score_kernel(const float* __restrict__ proj,
                                  const float* __restrict__ rel_emb,
                                  const int* __restrict__ head,
                                  const int* __restrict__ tail,
                                  const int* __restrict__ etype,
                                  float* __restrict__ ex, float* __restrict__ ssum,
                                  int E) {
    int lane = threadIdx.x & 63;
    int wid = (blockIdx.x * blockDim.x + threadIdx.x) >> 6;
    if (wid >= E) return;
    int h = head[wid], t = tail[wid], r = etype[wid] - 1;
    float ph = proj[(size_t)h * EMB + lane];
    float pt = proj[(size_t)t * EMB + lane];
    float rl = rel_emb[r * EMB + lane];
    float prod = ph * pt * rl;
    // independent 32-lane half reductions (head 0 = lanes 0..31, head 1 = 32..63)
#pragma unroll
    for (int m = 1; m <= 16; m <<= 1) prod += __shfl_xor(prod, m, 64);
    float exs = __expf(prod * INV_SQRT_DK);
    if (lane == 0)  { ex[(size_t)wid * 2 + 0] = exs; atomicAdd(&ssum[h * 2 + 0], exs); }
    if (lane == 32) { ex[(size_t)wid * 2 + 1] = exs; atomicAdd(&ssum[h * 2 + 1], exs); }
}

// ------------- edge aggregation: e_agg[head] += attn * (e[tail]*rel) -------------
__global__ void edge_agg_kernel(const float* __restrict__ e_in,
                                const float* __restrict__ rel_emb,
                                const int* __restrict__ head,
                                const int* __restrict__ tail,
                                const int* __restrict__ etype,
                                const float* __restrict__ ex,
                                const float* __restrict__ ssum,
                                float* __restrict__ e_agg, int E) {
    int lane = threadIdx.x & 63;
    int wid = (blockIdx.x * blockDim.x + threadIdx.x) >> 6;
    if (wid >= E) return;
    int h = head[wid], t = tail[wid], r = etype[wid] - 1;
    int hh = lane >> 5;
    float attn = ex[(size_t)wid * 2 + hh] / ssum[h * 2 + hh];
    float val = e_in[(size_t)t * EMB + lane] * rel_emb[r * EMB + lane];
    atomicAdd(&e_agg[(size_t)h * EMB + lane], val * attn);
}

// ------------- user aggregation: u_agg[u] += w * e[i] -------------
__global__ void ui_agg_kernel(const float* __restrict__ e_in,
                              const int* __restrict__ uidx,
                              const int* __restrict__ iidx,
                              const float* __restrict__ w,
                              float* __restrict__ u_agg, int E) {
    int lane = threadIdx.x & 63;
    int wid = (blockIdx.x * blockDim.x + threadIdx.x) >> 6;
    if (wid >= E) return;
    int u = uidx[wid], it = iidx[wid];
    float ww = w[wid];
    atomicAdd(&u_agg[(size_t)u * EMB + lane], ww * e_in[(size_t)it * EMB + lane]);
}

// ------------- L2 row-normalize; optionally emit normalized; res += -------------
__global__ void norm_acc_kernel(const float* __restrict__ agg,
                                float* __restrict__ out_norm,  // may be nullptr
                                float* __restrict__ res, int n) {
    int lane = threadIdx.x & 63;
    int wid = (blockIdx.x * blockDim.x + threadIdx.x) >> 6;
    if (wid >= n) return;
    float v = agg[(size_t)wid * EMB + lane];
    float s = v * v;
#pragma unroll
    for (int m = 1; m <= 32; m <<= 1) s += __shfl_xor(s, m, 64);
    float o = v / fmaxf(sqrtf(s), 1e-12f);
    if (out_norm) out_norm[(size_t)wid * EMB + lane] = o;
    res[(size_t)wid * EMB + lane] += o;
}

extern "C" void kernel_launch(void* const* d_in, const int* in_sizes, int n_in,
                              void* d_out, int out_size, void* d_ws, size_t ws_size,
                              hipStream_t stream) {
    const float* user_emb   = (const float*)d_in[0];
    const float* entity_emb = (const float*)d_in[1];
    const int*   edge_index = (const int*)d_in[2];   // [2, E]
    const int*   edge_type  = (const int*)d_in[3];   // [E]
    const int*   inter_edge = (const int*)d_in[4];   // [2, EI]
    const float* inter_w    = (const float*)d_in[5]; // [EI]
    const float* W_Q        = (const float*)d_in[6]; // [64,64]
    const float* rel_emb    = (const float*)d_in[7]; // [16,64]

    const int E     = in_sizes[3];
    const int EI    = in_sizes[5];
    const int n_ent = in_sizes[1] / EMB;
    const int n_usr = in_sizes[0] / EMB;

    const int* head = edge_index;
    const int* tail = edge_index + E;
    const int* iu   = inter_edge;
    const int* ii   = inter_edge + EI;

    // workspace layout (floats)
    float* ws    = (float*)d_ws;
    float* proj  = ws;                                  // n_ent*64
    float* ex    = proj  + (size_t)n_ent * EMB;         // E*2
    float* ssum  = ex    + (size_t)E * 2;               // n_ent*2
    float* e_agg = ssum  + (size_t)n_ent * 2;           // n_ent*64
    float* u_agg = e_agg + (size_t)n_ent * EMB;         // n_usr*64
    float* e_cur = u_agg + (size_t)n_usr * EMB;         // n_ent*64

    float* e_res = (float*)d_out;
    float* u_res = e_res + (size_t)n_ent * EMB;

    // residual init
    hipMemcpyAsync(e_res, entity_emb, (size_t)n_ent * EMB * 4, hipMemcpyDeviceToDevice, stream);
    hipMemcpyAsync(u_res, user_emb,   (size_t)n_usr * EMB * 4, hipMemcpyDeviceToDevice, stream);

    const float* e_in = entity_emb;
    for (int hop = 0; hop < 2; ++hop) {
        hipMemsetAsync(ssum,  0, (size_t)n_ent * 2 * 4, stream);
        hipMemsetAsync(e_agg, 0, (size_t)n_ent * EMB * 4, stream);
        hipMemsetAsync(u_agg, 0, (size_t)n_usr * EMB * 4, stream);

        proj_kernel<<<(n_ent + 3) / 4, 256, 0, stream>>>(e_in, W_Q, proj, n_ent);
        edge_score_kernel<<<(E + 3) / 4, 256, 0, stream>>>(proj, rel_emb, head, tail, edge_type,
                                                           ex, ssum, E);
        edge_agg_kernel<<<(E + 3) / 4, 256, 0, stream>>>(e_in, rel_emb, head, tail, edge_type,
                                                         ex, ssum, e_agg, E);
        ui_agg_kernel<<<(EI + 3) / 4, 256, 0, stream>>>(e_in, iu, ii, inter_w, u_agg, EI);
        norm_acc_kernel<<<(n_ent + 3) / 4, 256, 0, stream>>>(e_agg, e_cur, e_res, n_ent);
        norm_acc_kernel<<<(n_usr + 3) / 4, 256, 0, stream>>>(u_agg, nullptr, u_res, n_usr);

        e_in = e_cur;
    }
}

// Round 2
// 1626.255 us; speedup vs baseline: 1.4635x; 1.4635x over previous
//
#include <hip/hip_runtime.h>
#include <math.h>

#define EMB 64
static constexpr float INV_SQRT_DK = 0.17677669529663687f; // 1/sqrt(32)

// ---------------- proj = e @ W_Q (wave per row, W in LDS) ----------------
__global__ void proj_kernel(const float* __restrict__ e, const float* __restrict__ W,
                            float* __restrict__ proj, int n) {
    __shared__ float Wl[64 * 64];
    int t = threadIdx.x;
    for (int i = t; i < 64 * 64; i += blockDim.x) Wl[i] = W[i];
    __syncthreads();
    int lane = t & 63;
    int wavesPerBlock = blockDim.x >> 6;
    int wid = blockIdx.x * wavesPerBlock + (t >> 6);
    int nw = gridDim.x * wavesPerBlock;
    for (int r = wid; r < n; r += nw) {
        float x = e[(size_t)r * EMB + lane];
        float acc = 0.f;
#pragma unroll
        for (int k = 0; k < 64; ++k) {
            float ek = __shfl(x, k, 64);
            acc += ek * Wl[k * 64 + lane];
        }
        proj[(size_t)r * EMB + lane] = acc;
    }
}

// ---------------- CSR build: histogram ----------------
__global__ void hist_kernel(const int* __restrict__ idx, int* __restrict__ deg, int E) {
    int e = blockIdx.x * blockDim.x + threadIdx.x;
    if (e < E) atomicAdd(&deg[idx[e]], 1);
}

// ---------------- CSR build: single-block exclusive scan ----------------
__global__ void scan_kernel(const int* __restrict__ deg, int* __restrict__ off, int n) {
    __shared__ int part[1024];
    int t = threadIdx.x;                       // blockDim.x == 1024, gridDim.x == 1
    int chunk = (n + 1023) >> 10;
    int base = t * chunk;
    int s = 0;
    for (int i = 0; i < chunk; ++i) {
        int idx = base + i;
        if (idx < n) s += deg[idx];
    }
    part[t] = s;
    __syncthreads();
    for (int d = 1; d < 1024; d <<= 1) {       // Hillis-Steele inclusive scan
        int v = (t >= d) ? part[t - d] : 0;
        __syncthreads();
        part[t] += v;
        __syncthreads();
    }
    int prefix = (t == 0) ? 0 : part[t - 1];
    for (int i = 0; i < chunk; ++i) {
        int idx = base + i;
        if (idx < n) { off[idx] = prefix; prefix += deg[idx]; }
    }
    if (t == 1023) off[n] = part[1023];
}

// ---------------- CSR build: fill (KG: pack tail | type<<17) ----------------
__global__ void fill_kg_kernel(const int* __restrict__ head, const int* __restrict__ tail,
                               const int* __restrict__ etype,
                               int* __restrict__ cur, int* __restrict__ col, int E) {
    int e = blockIdx.x * blockDim.x + threadIdx.x;
    if (e >= E) return;
    int pos = atomicAdd(&cur[head[e]], 1);
    col[pos] = tail[e] | ((etype[e] - 1) << 17);   // tail < 2^17, type in [0,16)
}

__global__ void fill_ui_kernel(const int* __restrict__ uu, const int* __restrict__ ii,
                               const float* __restrict__ w,
                               int* __restrict__ cur, int* __restrict__ coli,
                               float* __restrict__ colw, int E) {
    int e = blockIdx.x * blockDim.x + threadIdx.x;
    if (e >= E) return;
    int pos = atomicAdd(&cur[uu[e]], 1);
    coli[pos] = ii[e];
    colw[pos] = w[e];
}

// ------- fused per-node: attention softmax (in-register) + agg + l2norm + residual -------
template <bool WRITE_CUR>
__global__ void kg_agg_kernel(const float* __restrict__ proj, const float* __restrict__ e_in,
                              const float* __restrict__ rel_emb,
                              const int* __restrict__ off, const int* __restrict__ col,
                              float* __restrict__ e_cur, float* __restrict__ e_res, int n) {
    __shared__ float relS[16 * EMB];
    int t = threadIdx.x;
    for (int i = t; i < 16 * EMB; i += blockDim.x) relS[i] = rel_emb[i];
    __syncthreads();
    int lane = t & 63;
    int wid = blockIdx.x * (blockDim.x >> 6) + (t >> 6);
    if (wid >= n) return;
    int s = off[wid], e = off[wid + 1];
    float q = proj[(size_t)wid * EMB + lane];
    float num = 0.f, den = 0.f;
    for (int j = s; j < e; ++j) {
        int p = col[j];
        int tt = p & 131071;
        int r  = p >> 17;
        float rl = relS[r * EMB + lane];
        float pt = proj[(size_t)tt * EMB + lane];
        float et = e_in[(size_t)tt * EMB + lane];
        float prod = q * pt * rl;
        // per-head (32-lane half) reduction; every lane ends with its half's score
#pragma unroll
        for (int m = 1; m <= 16; m <<= 1) prod += __shfl_xor(prod, m, 64);
        float ex = __expf(prod * INV_SQRT_DK);
        den += ex;
        num += ex * et * rl;
    }
    float v = (e > s) ? num / den : 0.f;       // deferred softmax division
    float ss = v * v;
#pragma unroll
    for (int m = 1; m <= 32; m <<= 1) ss += __shfl_xor(ss, m, 64);
    float o = v / fmaxf(sqrtf(ss), 1e-12f);
    if (WRITE_CUR) e_cur[(size_t)wid * EMB + lane] = o;
    e_res[(size_t)wid * EMB + lane] += o;
}

// ------- fused per-user: weighted agg (in-register) + l2norm + residual -------
__global__ void ui_agg_kernel(const float* __restrict__ e_in,
                              const int* __restrict__ off, const int* __restrict__ coli,
                              const float* __restrict__ colw,
                              float* __restrict__ u_res, int n) {
    int t = threadIdx.x;
    int lane = t & 63;
    int wid = blockIdx.x * (blockDim.x >> 6) + (t >> 6);
    if (wid >= n) return;
    int s = off[wid], e = off[wid + 1];
    float acc = 0.f;
    for (int j = s; j < e; ++j) {
        acc += colw[j] * e_in[(size_t)coli[j] * EMB + lane];
    }
    float ss = acc * acc;
#pragma unroll
    for (int m = 1; m <= 32; m <<= 1) ss += __shfl_xor(ss, m, 64);
    float o = acc / fmaxf(sqrtf(ss), 1e-12f);
    u_res[(size_t)wid * EMB + lane] += o;
}

extern "C" void kernel_launch(void* const* d_in, const int* in_sizes, int n_in,
                              void* d_out, int out_size, void* d_ws, size_t ws_size,
                              hipStream_t stream) {
    const float* user_emb   = (const float*)d_in[0];
    const float* entity_emb = (const float*)d_in[1];
    const int*   edge_index = (const int*)d_in[2];   // [2, E]
    const int*   edge_type  = (const int*)d_in[3];   // [E]
    const int*   inter_edge = (const int*)d_in[4];   // [2, EI]
    const float* inter_w    = (const float*)d_in[5]; // [EI]
    const float* W_Q        = (const float*)d_in[6]; // [64,64]
    const float* rel_emb    = (const float*)d_in[7]; // [16,64]

    const int E     = in_sizes[3];
    const int EI    = in_sizes[5];
    const int n_ent = in_sizes[1] / EMB;
    const int n_usr = in_sizes[0] / EMB;

    const int* head = edge_index;
    const int* tail = edge_index + E;
    const int* iu   = inter_edge;
    const int* ii   = inter_edge + EI;

    // ---- workspace layout ----
    char* ws = (char*)d_ws;
    float* proj  = (float*)ws;                 ws += (size_t)n_ent * EMB * 4;
    float* e_cur = (float*)ws;                 ws += (size_t)n_ent * EMB * 4;
    int*   col_h = (int*)ws;                   ws += (size_t)E * 4;
    int*   col_i = (int*)ws;                   ws += (size_t)EI * 4;
    float* col_w = (float*)ws;                 ws += (size_t)EI * 4;
    int*   off_h = (int*)ws;                   ws += (size_t)(n_ent + 1) * 4;
    int*   cur_h = (int*)ws;                   ws += (size_t)n_ent * 4;
    int*   off_u = (int*)ws;                   ws += (size_t)(n_usr + 1) * 4;
    int*   cur_u = (int*)ws;                   ws += (size_t)n_usr * 4;

    float* e_res = (float*)d_out;
    float* u_res = e_res + (size_t)n_ent * EMB;

    // residual init
    hipMemcpyAsync(e_res, entity_emb, (size_t)n_ent * EMB * 4, hipMemcpyDeviceToDevice, stream);
    hipMemcpyAsync(u_res, user_emb,   (size_t)n_usr * EMB * 4, hipMemcpyDeviceToDevice, stream);

    // ---- CSR build (once; reused by both hops) ----
    hipMemsetAsync(cur_h, 0, (size_t)n_ent * 4, stream);
    hipMemsetAsync(cur_u, 0, (size_t)n_usr * 4, stream);
    hist_kernel<<<(E + 255) / 256, 256, 0, stream>>>(head, cur_h, E);
    hist_kernel<<<(EI + 255) / 256, 256, 0, stream>>>(iu, cur_u, EI);
    scan_kernel<<<1, 1024, 0, stream>>>(cur_h, off_h, n_ent);
    scan_kernel<<<1, 1024, 0, stream>>>(cur_u, off_u, n_usr);
    hipMemcpyAsync(cur_h, off_h, (size_t)n_ent * 4, hipMemcpyDeviceToDevice, stream);
    hipMemcpyAsync(cur_u, off_u, (size_t)n_usr * 4, hipMemcpyDeviceToDevice, stream);
    fill_kg_kernel<<<(E + 255) / 256, 256, 0, stream>>>(head, tail, edge_type, cur_h, col_h, E);
    fill_ui_kernel<<<(EI + 255) / 256, 256, 0, stream>>>(iu, ii, inter_w, cur_u, col_i, col_w, EI);

    const int kgBlocks = (n_ent + 3) / 4;
    const int uiBlocks = (n_usr + 3) / 4;

    // ---- hop 1 (e_in = entity_emb) ----
    proj_kernel<<<(n_ent + 3) / 4, 256, 0, stream>>>(entity_emb, W_Q, proj, n_ent);
    kg_agg_kernel<true><<<kgBlocks, 256, 0, stream>>>(proj, entity_emb, rel_emb,
                                                      off_h, col_h, e_cur, e_res, n_ent);
    ui_agg_kernel<<<uiBlocks, 256, 0, stream>>>(entity_emb, off_u, col_i, col_w, u_res, n_usr);

    // ---- hop 2 (e_in = e_cur; no need to emit normalized e) ----
    proj_kernel<<<(n_ent + 3) / 4, 256, 0, stream>>>(e_cur, W_Q, proj, n_ent);
    kg_agg_kernel<false><<<kgBlocks, 256, 0, stream>>>(proj, e_cur, rel_emb,
                                                       off_h, col_h, nullptr, e_res, n_ent);
    ui_agg_kernel<<<uiBlocks, 256, 0, stream>>>(e_cur, off_u, col_i, col_w, u_res, n_usr);
}

// Round 3
// 1590.849 us; speedup vs baseline: 1.4961x; 1.0223x over previous
//
#include <hip/hip_runtime.h>
#include <math.h>

#define EMB 64
static constexpr float INV_SQRT_DK = 0.17677669529663687f; // 1/sqrt(32)

__device__ inline unsigned short f2bf(float f) {
    union { float f; unsigned u; } v; v.f = f;
    unsigned r = v.u + 0x7FFF + ((v.u >> 16) & 1);   // round-to-nearest-even
    return (unsigned short)(r >> 16);
}
__device__ inline float bf2f(unsigned short b) {
    union { float f; unsigned u; } v; v.u = ((unsigned)b) << 16;
    return v.f;
}

// ---- proj = e @ W_Q; emit bf16 proj and bf16 e (gather tables) ----
__global__ void proj_pack_kernel(const float* __restrict__ e, const float* __restrict__ W,
                                 unsigned short* __restrict__ proj_bf,
                                 unsigned short* __restrict__ e_bf, int n) {
    __shared__ float Wl[64 * 64];
    int t = threadIdx.x;
    for (int i = t; i < 64 * 64; i += blockDim.x) Wl[i] = W[i];
    __syncthreads();
    int lane = t & 63;
    int wavesPerBlock = blockDim.x >> 6;
    int wid = blockIdx.x * wavesPerBlock + (t >> 6);
    int nw = gridDim.x * wavesPerBlock;
    for (int r = wid; r < n; r += nw) {
        float x = e[(size_t)r * EMB + lane];
        float acc = 0.f;
#pragma unroll
        for (int k = 0; k < 64; ++k) {
            float ek = __shfl(x, k, 64);
            acc += ek * Wl[k * 64 + lane];
        }
        proj_bf[(size_t)r * EMB + lane] = f2bf(acc);
        e_bf[(size_t)r * EMB + lane]    = f2bf(x);
    }
}

// ---------------- CSR build: histogram ----------------
__global__ void hist_kernel(const int* __restrict__ idx, int* __restrict__ deg, int E) {
    int e = blockIdx.x * blockDim.x + threadIdx.x;
    if (e < E) atomicAdd(&deg[idx[e]], 1);
}

// ---------------- CSR build: single-block exclusive scan ----------------
__global__ void scan_kernel(const int* __restrict__ deg, int* __restrict__ off, int n) {
    __shared__ int part[1024];
    int t = threadIdx.x;                       // blockDim.x == 1024, gridDim.x == 1
    int chunk = (n + 1023) >> 10;
    int base = t * chunk;
    int s = 0;
    for (int i = 0; i < chunk; ++i) {
        int idx = base + i;
        if (idx < n) s += deg[idx];
    }
    part[t] = s;
    __syncthreads();
    for (int d = 1; d < 1024; d <<= 1) {       // Hillis-Steele inclusive scan
        int v = (t >= d) ? part[t - d] : 0;
        __syncthreads();
        part[t] += v;
        __syncthreads();
    }
    int prefix = (t == 0) ? 0 : part[t - 1];
    for (int i = 0; i < chunk; ++i) {
        int idx = base + i;
        if (idx < n) { off[idx] = prefix; prefix += deg[idx]; }
    }
    if (t == 1023) off[n] = part[1023];
}

// ---------------- CSR build: fill (KG: pack tail | type<<17) ----------------
__global__ void fill_kg_kernel(const int* __restrict__ head, const int* __restrict__ tail,
                               const int* __restrict__ etype,
                               int* __restrict__ cur, int* __restrict__ col, int E) {
    int e = blockIdx.x * blockDim.x + threadIdx.x;
    if (e >= E) return;
    int pos = atomicAdd(&cur[head[e]], 1);
    col[pos] = tail[e] | ((etype[e] - 1) << 17);   // tail < 2^17, type in [0,16)
}

__global__ void fill_ui_kernel(const int* __restrict__ uu, const int* __restrict__ ii,
                               const float* __restrict__ w,
                               int* __restrict__ cur, int* __restrict__ coli,
                               float* __restrict__ colw, int E) {
    int e = blockIdx.x * blockDim.x + threadIdx.x;
    if (e >= E) return;
    int pos = atomicAdd(&cur[uu[e]], 1);
    coli[pos] = ii[e];
    colw[pos] = w[e];
}

// ------- fused per-node: attention softmax (in-register) + agg + l2norm + residual -------
template <bool HOP1>
__global__ void kg_agg_kernel(const unsigned short* __restrict__ proj_bf,
                              const unsigned short* __restrict__ e_bf,
                              const float* __restrict__ rel_emb,
                              const int* __restrict__ off, const int* __restrict__ col,
                              const float* __restrict__ e_base,   // entity_emb (hop1 only)
                              float* __restrict__ e_cur,          // hop1 only
                              float* __restrict__ e_res, int n) {
    __shared__ float relS[16 * EMB];
    int t = threadIdx.x;
    for (int i = t; i < 16 * EMB; i += blockDim.x) relS[i] = rel_emb[i];
    __syncthreads();
    int lane = t & 63;
    int wid = blockIdx.x * (blockDim.x >> 6) + (t >> 6);
    if (wid >= n) return;
    int s = off[wid], e = off[wid + 1];
    float q = bf2f(proj_bf[(size_t)wid * EMB + lane]);
    float num = 0.f, den = 0.f;
    for (int j = s; j < e; ++j) {
        int p = col[j];
        int tt = p & 131071;
        int r  = p >> 17;
        float rl = relS[r * EMB + lane];
        float pt = bf2f(proj_bf[(size_t)tt * EMB + lane]);
        float et = bf2f(e_bf[(size_t)tt * EMB + lane]);
        float prod = q * pt * rl;
        // per-head (32-lane half) reduction; every lane ends with its half's score
#pragma unroll
        for (int m = 1; m <= 16; m <<= 1) prod += __shfl_xor(prod, m, 64);
        float ex = __expf(prod * INV_SQRT_DK);
        den += ex;
        num += ex * et * rl;
    }
    float v = (e > s) ? num / den : 0.f;       // deferred softmax division
    float ss = v * v;
#pragma unroll
    for (int m = 1; m <= 32; m <<= 1) ss += __shfl_xor(ss, m, 64);
    float o = v / fmaxf(sqrtf(ss), 1e-12f);
    size_t ix = (size_t)wid * EMB + lane;
    if (HOP1) {
        e_cur[ix] = o;
        e_res[ix] = e_base[ix] + o;            // residual init folded in
    } else {
        e_res[ix] += o;
    }
}

// ------- fused per-user: weighted agg (in-register) + l2norm + residual -------
template <bool HOP1>
__global__ void ui_agg_kernel(const unsigned short* __restrict__ e_bf,
                              const int* __restrict__ off, const int* __restrict__ coli,
                              const float* __restrict__ colw,
                              const float* __restrict__ u_base,   // user_emb (hop1 only)
                              float* __restrict__ u_res, int n) {
    int t = threadIdx.x;
    int lane = t & 63;
    int wid = blockIdx.x * (blockDim.x >> 6) + (t >> 6);
    if (wid >= n) return;
    int s = off[wid], e = off[wid + 1];
    float acc = 0.f;
    for (int j = s; j < e; ++j) {
        acc += colw[j] * bf2f(e_bf[(size_t)coli[j] * EMB + lane]);
    }
    float ss = acc * acc;
#pragma unroll
    for (int m = 1; m <= 32; m <<= 1) ss += __shfl_xor(ss, m, 64);
    float o = acc / fmaxf(sqrtf(ss), 1e-12f);
    size_t ix = (size_t)wid * EMB + lane;
    if (HOP1) u_res[ix] = u_base[ix] + o;
    else      u_res[ix] += o;
}

extern "C" void kernel_launch(void* const* d_in, const int* in_sizes, int n_in,
                              void* d_out, int out_size, void* d_ws, size_t ws_size,
                              hipStream_t stream) {
    const float* user_emb   = (const float*)d_in[0];
    const float* entity_emb = (const float*)d_in[1];
    const int*   edge_index = (const int*)d_in[2];   // [2, E]
    const int*   edge_type  = (const int*)d_in[3];   // [E]
    const int*   inter_edge = (const int*)d_in[4];   // [2, EI]
    const float* inter_w    = (const float*)d_in[5]; // [EI]
    const float* W_Q        = (const float*)d_in[6]; // [64,64]
    const float* rel_emb    = (const float*)d_in[7]; // [16,64]

    const int E     = in_sizes[3];
    const int EI    = in_sizes[5];
    const int n_ent = in_sizes[1] / EMB;
    const int n_usr = in_sizes[0] / EMB;

    const int* head = edge_index;
    const int* tail = edge_index + E;
    const int* iu   = inter_edge;
    const int* ii   = inter_edge + EI;

    // ---- workspace layout ----
    char* ws = (char*)d_ws;
    unsigned short* proj_bf = (unsigned short*)ws;  ws += (size_t)n_ent * EMB * 2;
    unsigned short* e_bf    = (unsigned short*)ws;  ws += (size_t)n_ent * EMB * 2;
    float* e_cur = (float*)ws;                 ws += (size_t)n_ent * EMB * 4;
    int*   col_h = (int*)ws;                   ws += (size_t)E * 4;
    int*   col_i = (int*)ws;                   ws += (size_t)EI * 4;
    float* col_w = (float*)ws;                 ws += (size_t)EI * 4;
    int*   off_h = (int*)ws;                   ws += (size_t)(n_ent + 1) * 4;
    int*   cur_h = (int*)ws;                   ws += (size_t)n_ent * 4;
    int*   off_u = (int*)ws;                   ws += (size_t)(n_usr + 1) * 4;
    int*   cur_u = (int*)ws;                   ws += (size_t)n_usr * 4;

    float* e_res = (float*)d_out;
    float* u_res = e_res + (size_t)n_ent * EMB;

    // ---- CSR build (once; reused by both hops) ----
    hipMemsetAsync(cur_h, 0, (size_t)n_ent * 4, stream);
    hipMemsetAsync(cur_u, 0, (size_t)n_usr * 4, stream);
    hist_kernel<<<(E + 255) / 256, 256, 0, stream>>>(head, cur_h, E);
    hist_kernel<<<(EI + 255) / 256, 256, 0, stream>>>(iu, cur_u, EI);
    scan_kernel<<<1, 1024, 0, stream>>>(cur_h, off_h, n_ent);
    scan_kernel<<<1, 1024, 0, stream>>>(cur_u, off_u, n_usr);
    hipMemcpyAsync(cur_h, off_h, (size_t)n_ent * 4, hipMemcpyDeviceToDevice, stream);
    hipMemcpyAsync(cur_u, off_u, (size_t)n_usr * 4, hipMemcpyDeviceToDevice, stream);
    fill_kg_kernel<<<(E + 255) / 256, 256, 0, stream>>>(head, tail, edge_type, cur_h, col_h, E);
    fill_ui_kernel<<<(EI + 255) / 256, 256, 0, stream>>>(iu, ii, inter_w, cur_u, col_i, col_w, EI);

    const int kgBlocks = (n_ent + 3) / 4;
    const int uiBlocks = (n_usr + 3) / 4;

    // ---- hop 1 (e_in = entity_emb) ----
    proj_pack_kernel<<<(n_ent + 3) / 4, 256, 0, stream>>>(entity_emb, W_Q, proj_bf, e_bf, n_ent);
    kg_agg_kernel<true><<<kgBlocks, 256, 0, stream>>>(proj_bf, e_bf, rel_emb,
                                                      off_h, col_h, entity_emb, e_cur, e_res, n_ent);
    ui_agg_kernel<true><<<uiBlocks, 256, 0, stream>>>(e_bf, off_u, col_i, col_w, user_emb, u_res, n_usr);

    // ---- hop 2 (e_in = e_cur) ----
    proj_pack_kernel<<<(n_ent + 3) / 4, 256, 0, stream>>>(e_cur, W_Q, proj_bf, e_bf, n_ent);
    kg_agg_kernel<false><<<kgBlocks, 256, 0, stream>>>(proj_bf, e_bf, rel_emb,
                                                       off_h, col_h, nullptr, nullptr, e_res, n_ent);
    ui_agg_kernel<false><<<uiBlocks, 256, 0, stream>>>(e_bf, off_u, col_i, col_w, nullptr, u_res, n_usr);
}

// Round 4
// 1246.891 us; speedup vs baseline: 1.9088x; 1.2759x over previous
//
#include <hip/hip_runtime.h>
#include <math.h>

#define EMB 64
static constexpr float INV_SQRT_DK = 0.17677669529663687f; // 1/sqrt(32)

__device__ inline unsigned short f2bf(float f) {
    union { float f; unsigned u; } v; v.f = f;
    unsigned r = v.u + 0x7FFF + ((v.u >> 16) & 1);   // round-to-nearest-even
    return (unsigned short)(r >> 16);
}
__device__ inline float bfhi(unsigned w) {           // high 16 bits as bf16
    union { float f; unsigned u; } v; v.u = w & 0xFFFF0000u; return v.f;
}
__device__ inline float bflo(unsigned w) {           // low 16 bits as bf16
    union { float f; unsigned u; } v; v.u = w << 16; return v.f;
}
__device__ inline float bf2f(unsigned short b) {
    union { float f; unsigned u; } v; v.u = ((unsigned)b) << 16; return v.f;
}

// ---- proj = e @ W_Q; emit packed (proj<<16|e) and e_bf gather tables ----
__global__ void proj_pack_kernel(const float* __restrict__ e, const float* __restrict__ W,
                                 unsigned* __restrict__ packed,
                                 unsigned short* __restrict__ e_bf, int n) {
    __shared__ float Wl[64 * 64];
    int t = threadIdx.x;
    for (int i = t; i < 64 * 64; i += blockDim.x) Wl[i] = W[i];
    __syncthreads();
    int lane = t & 63;
    int wavesPerBlock = blockDim.x >> 6;
    int wid = blockIdx.x * wavesPerBlock + (t >> 6);
    int nw = gridDim.x * wavesPerBlock;
    for (int r = wid; r < n; r += nw) {
        float x = e[(size_t)r * EMB + lane];
        float acc = 0.f;
#pragma unroll
        for (int k = 0; k < 64; ++k) {
            float ek = __shfl(x, k, 64);
            acc += ek * Wl[k * 64 + lane];
        }
        unsigned pb = f2bf(acc), eb = f2bf(x);
        size_t ix = (size_t)r * EMB + lane;
        packed[ix] = (pb << 16) | eb;
        e_bf[ix] = (unsigned short)eb;
    }
}

// ---------------- CSR build ----------------
__global__ void hist_kernel(const int* __restrict__ idx, int* __restrict__ deg, int E) {
    int e = blockIdx.x * blockDim.x + threadIdx.x;
    if (e < E) atomicAdd(&deg[idx[e]], 1);
}

__global__ void scan_kernel(const int* __restrict__ deg, int* __restrict__ off, int n) {
    __shared__ int part[1024];
    int t = threadIdx.x;                       // blockDim.x == 1024, gridDim.x == 1
    int chunk = (n + 1023) >> 10;
    int base = t * chunk;
    int s = 0;
    for (int i = 0; i < chunk; ++i) {
        int idx = base + i;
        if (idx < n) s += deg[idx];
    }
    part[t] = s;
    __syncthreads();
    for (int d = 1; d < 1024; d <<= 1) {
        int v = (t >= d) ? part[t - d] : 0;
        __syncthreads();
        part[t] += v;
        __syncthreads();
    }
    int prefix = (t == 0) ? 0 : part[t - 1];
    for (int i = 0; i < chunk; ++i) {
        int idx = base + i;
        if (idx < n) { off[idx] = prefix; prefix += deg[idx]; }
    }
    if (t == 1023) off[n] = part[1023];
}

__global__ void fill_kg_kernel(const int* __restrict__ head, const int* __restrict__ tail,
                               const int* __restrict__ etype,
                               int* __restrict__ cur, int* __restrict__ col, int E) {
    int e = blockIdx.x * blockDim.x + threadIdx.x;
    if (e >= E) return;
    int pos = atomicAdd(&cur[head[e]], 1);
    col[pos] = tail[e] | ((etype[e] - 1) << 17);   // tail < 2^17, type in [0,16)
}

__global__ void fill_ui_kernel(const int* __restrict__ uu, const int* __restrict__ ii,
                               const float* __restrict__ w,
                               int* __restrict__ cur, int* __restrict__ coli,
                               float* __restrict__ colw, int E) {
    int e = blockIdx.x * blockDim.x + threadIdx.x;
    if (e >= E) return;
    int pos = atomicAdd(&cur[uu[e]], 1);
    coli[pos] = ii[e];
    colw[pos] = w[e];
}

// ------- fused: per-entity attention agg  +  per-user weighted agg, one kernel -------
#define KG_EDGE(pw, rr) {                                                  \
        float rl = relS[(rr) * EMB + lane];                                \
        float pt = bfhi(pw), et = bflo(pw);                                \
        float prod = q * pt * rl;                                          \
        prod += __shfl_xor(prod, 1, 64);                                   \
        prod += __shfl_xor(prod, 2, 64);                                   \
        prod += __shfl_xor(prod, 4, 64);                                   \
        prod += __shfl_xor(prod, 8, 64);                                   \
        prod += __shfl_xor(prod, 16, 64);                                  \
        float ex = __expf(prod * INV_SQRT_DK);                             \
        den += ex;                                                         \
        num = fmaf(ex * rl, et, num); }

template <bool HOP1>
__global__ void agg_fused_kernel(const unsigned* __restrict__ packed,
                                 const unsigned short* __restrict__ e_bf,
                                 const float* __restrict__ rel_emb,
                                 const int* __restrict__ off_h, const int* __restrict__ col_h,
                                 const int* __restrict__ off_u, const int* __restrict__ col_i,
                                 const float* __restrict__ col_w,
                                 const float* __restrict__ e_base, float* __restrict__ e_cur,
                                 float* __restrict__ e_res, int n_ent,
                                 const float* __restrict__ u_base, float* __restrict__ u_res,
                                 int n_usr, int kgBlocks, int totalBlocks) {
    __shared__ float relS[16 * EMB];
    int bid = blockIdx.x;
    // Bresenham interleave of kg-role and ui-role blocks
    size_t lo = (size_t)bid * kgBlocks / totalBlocks;
    size_t hi = (size_t)(bid + 1) * kgBlocks / totalBlocks;
    int lane = threadIdx.x & 63;
    int wslot = threadIdx.x >> 6;

    if (hi > lo) {
        // ---------------- KG entity block ----------------
        for (int i = threadIdx.x; i < 16 * EMB; i += blockDim.x) relS[i] = rel_emb[i];
        __syncthreads();
        int wid = (int)lo * 4 + wslot;
        if (wid >= n_ent) return;
        int s = off_h[wid], e = off_h[wid + 1];
        float q = bfhi(packed[(size_t)wid * EMB + lane]);
        float num = 0.f, den = 0.f;
        int j = s;
        for (; j + 3 < e; j += 4) {
            int p0 = col_h[j], p1 = col_h[j + 1], p2 = col_h[j + 2], p3 = col_h[j + 3];
            unsigned w0 = packed[(size_t)(p0 & 131071) * EMB + lane];
            unsigned w1 = packed[(size_t)(p1 & 131071) * EMB + lane];
            unsigned w2 = packed[(size_t)(p2 & 131071) * EMB + lane];
            unsigned w3 = packed[(size_t)(p3 & 131071) * EMB + lane];
            KG_EDGE(w0, p0 >> 17);
            KG_EDGE(w1, p1 >> 17);
            KG_EDGE(w2, p2 >> 17);
            KG_EDGE(w3, p3 >> 17);
        }
        for (; j < e; ++j) {
            int p = col_h[j];
            unsigned w = packed[(size_t)(p & 131071) * EMB + lane];
            KG_EDGE(w, p >> 17);
        }
        float v = (e > s) ? num / den : 0.f;       // deferred softmax division
        float ss = v * v;
#pragma unroll
        for (int m = 1; m <= 32; m <<= 1) ss += __shfl_xor(ss, m, 64);
        float o = v / fmaxf(sqrtf(ss), 1e-12f);
        size_t ix = (size_t)wid * EMB + lane;
        if (HOP1) {
            e_cur[ix] = o;
            e_res[ix] = e_base[ix] + o;
        } else {
            e_res[ix] += o;
        }
    } else {
        // ---------------- UI user block ----------------
        int wid = (bid - (int)lo) * 4 + wslot;
        if (wid >= n_usr) return;
        int s = off_u[wid], e = off_u[wid + 1];
        float acc = 0.f;
        int j = s;
        for (; j + 3 < e; j += 4) {
            int i0 = col_i[j], i1 = col_i[j + 1], i2 = col_i[j + 2], i3 = col_i[j + 3];
            float w0 = col_w[j], w1 = col_w[j + 1], w2 = col_w[j + 2], w3 = col_w[j + 3];
            float v0 = bf2f(e_bf[(size_t)i0 * EMB + lane]);
            float v1 = bf2f(e_bf[(size_t)i1 * EMB + lane]);
            float v2 = bf2f(e_bf[(size_t)i2 * EMB + lane]);
            float v3 = bf2f(e_bf[(size_t)i3 * EMB + lane]);
            acc = fmaf(w0, v0, acc);
            acc = fmaf(w1, v1, acc);
            acc = fmaf(w2, v2, acc);
            acc = fmaf(w3, v3, acc);
        }
        for (; j < e; ++j)
            acc = fmaf(col_w[j], bf2f(e_bf[(size_t)col_i[j] * EMB + lane]), acc);
        float ss = acc * acc;
#pragma unroll
        for (int m = 1; m <= 32; m <<= 1) ss += __shfl_xor(ss, m, 64);
        float o = acc / fmaxf(sqrtf(ss), 1e-12f);
        size_t ix = (size_t)wid * EMB + lane;
        if (HOP1) u_res[ix] = u_base[ix] + o;
        else      u_res[ix] += o;
    }
}

extern "C" void kernel_launch(void* const* d_in, const int* in_sizes, int n_in,
                              void* d_out, int out_size, void* d_ws, size_t ws_size,
                              hipStream_t stream) {
    const float* user_emb   = (const float*)d_in[0];
    const float* entity_emb = (const float*)d_in[1];
    const int*   edge_index = (const int*)d_in[2];   // [2, E]
    const int*   edge_type  = (const int*)d_in[3];   // [E]
    const int*   inter_edge = (const int*)d_in[4];   // [2, EI]
    const float* inter_w    = (const float*)d_in[5]; // [EI]
    const float* W_Q        = (const float*)d_in[6]; // [64,64]
    const float* rel_emb    = (const float*)d_in[7]; // [16,64]

    const int E     = in_sizes[3];
    const int EI    = in_sizes[5];
    const int n_ent = in_sizes[1] / EMB;
    const int n_usr = in_sizes[0] / EMB;

    const int* head = edge_index;
    const int* tail = edge_index + E;
    const int* iu   = inter_edge;
    const int* ii   = inter_edge + EI;

    // ---- workspace layout ----
    char* ws = (char*)d_ws;
    unsigned* packed        = (unsigned*)ws;        ws += (size_t)n_ent * EMB * 4;
    unsigned short* e_bf    = (unsigned short*)ws;  ws += (size_t)n_ent * EMB * 2;
    float* e_cur = (float*)ws;                 ws += (size_t)n_ent * EMB * 4;
    int*   col_h = (int*)ws;                   ws += (size_t)E * 4;
    int*   col_i = (int*)ws;                   ws += (size_t)EI * 4;
    float* col_w = (float*)ws;                 ws += (size_t)EI * 4;
    int*   off_h = (int*)ws;                   ws += (size_t)(n_ent + 1) * 4;
    int*   cur_h = (int*)ws;                   ws += (size_t)n_ent * 4;
    int*   off_u = (int*)ws;                   ws += (size_t)(n_usr + 1) * 4;
    int*   cur_u = (int*)ws;                   ws += (size_t)n_usr * 4;

    float* e_res = (float*)d_out;
    float* u_res = e_res + (size_t)n_ent * EMB;

    // ---- CSR build (once; reused by both hops) ----
    hipMemsetAsync(cur_h, 0, (size_t)n_ent * 4, stream);
    hipMemsetAsync(cur_u, 0, (size_t)n_usr * 4, stream);
    hist_kernel<<<(E + 255) / 256, 256, 0, stream>>>(head, cur_h, E);
    hist_kernel<<<(EI + 255) / 256, 256, 0, stream>>>(iu, cur_u, EI);
    scan_kernel<<<1, 1024, 0, stream>>>(cur_h, off_h, n_ent);
    scan_kernel<<<1, 1024, 0, stream>>>(cur_u, off_u, n_usr);
    hipMemcpyAsync(cur_h, off_h, (size_t)n_ent * 4, hipMemcpyDeviceToDevice, stream);
    hipMemcpyAsync(cur_u, off_u, (size_t)n_usr * 4, hipMemcpyDeviceToDevice, stream);
    fill_kg_kernel<<<(E + 255) / 256, 256, 0, stream>>>(head, tail, edge_type, cur_h, col_h, E);
    fill_ui_kernel<<<(EI + 255) / 256, 256, 0, stream>>>(iu, ii, inter_w, cur_u, col_i, col_w, EI);

    const int kgBlocks = (n_ent + 3) / 4;
    const int uiBlocks = (n_usr + 3) / 4;
    const int totalBlocks = kgBlocks + uiBlocks;

    // ---- hop 1 (e_in = entity_emb) ----
    proj_pack_kernel<<<kgBlocks, 256, 0, stream>>>(entity_emb, W_Q, packed, e_bf, n_ent);
    agg_fused_kernel<true><<<totalBlocks, 256, 0, stream>>>(
        packed, e_bf, rel_emb, off_h, col_h, off_u, col_i, col_w,
        entity_emb, e_cur, e_res, n_ent, user_emb, u_res, n_usr, kgBlocks, totalBlocks);

    // ---- hop 2 (e_in = e_cur) ----
    proj_pack_kernel<<<kgBlocks, 256, 0, stream>>>(e_cur, W_Q, packed, e_bf, n_ent);
    agg_fused_kernel<false><<<totalBlocks, 256, 0, stream>>>(
        packed, e_bf, rel_emb, off_h, col_h, off_u, col_i, col_w,
        nullptr, nullptr, e_res, n_ent, nullptr, u_res, n_usr, kgBlocks, totalBlocks);
}

// Round 5
// 994.565 us; speedup vs baseline: 2.3931x; 1.2537x over previous
//
#include <hip/hip_runtime.h>
#include <math.h>

#define EMB 64
static constexpr float INV_SQRT_DK = 0.17677669529663687f; // 1/sqrt(32)

__device__ inline unsigned short f2bf(float f) {
    union { float f; unsigned u; } v; v.f = f;
    unsigned r = v.u + 0x7FFF + ((v.u >> 16) & 1);   // round-to-nearest-even
    return (unsigned short)(r >> 16);
}
__device__ inline float bfhi(unsigned w) {           // high 16 bits as bf16
    union { float f; unsigned u; } v; v.u = w & 0xFFFF0000u; return v.f;
}
__device__ inline float bflo(unsigned w) {           // low 16 bits as bf16
    union { float f; unsigned u; } v; v.u = w << 16; return v.f;
}
__device__ inline float bf2f(unsigned short b) {
    union { float f; unsigned u; } v; v.u = ((unsigned)b) << 16; return v.f;
}

// ---- proj = e @ W_Q; emit packed (proj<<16|e) and e_bf gather tables ----
__global__ void proj_pack_kernel(const float* __restrict__ e, const float* __restrict__ W,
                                 unsigned* __restrict__ packed,
                                 unsigned short* __restrict__ e_bf, int n) {
    __shared__ float Wl[64 * 64];
    int t = threadIdx.x;
    for (int i = t; i < 64 * 64; i += blockDim.x) Wl[i] = W[i];
    __syncthreads();
    int lane = t & 63;
    int wavesPerBlock = blockDim.x >> 6;
    int wid = blockIdx.x * wavesPerBlock + (t >> 6);
    int nw = gridDim.x * wavesPerBlock;
    for (int r = wid; r < n; r += nw) {
        float x = e[(size_t)r * EMB + lane];
        float acc = 0.f;
#pragma unroll
        for (int k = 0; k < 64; ++k) {
            float ek = __shfl(x, k, 64);
            acc += ek * Wl[k * 64 + lane];
        }
        unsigned pb = f2bf(acc), eb = f2bf(x);
        size_t ix = (size_t)r * EMB + lane;
        packed[ix] = (pb << 16) | eb;
        e_bf[ix] = (unsigned short)eb;
    }
}

// ---------------- CSR build: histogram ----------------
__global__ void hist_kernel(const int* __restrict__ idx, int* __restrict__ deg, int E) {
    int e = blockIdx.x * blockDim.x + threadIdx.x;
    if (e < E) atomicAdd(&deg[idx[e]], 1);
}

// ---------------- multi-block exclusive scan (3 phases, 1024 elems/block) ----------------
__global__ void scan_partial_kernel(const int* __restrict__ deg, int* __restrict__ part, int n) {
    int base = blockIdx.x * 1024;
    int t = threadIdx.x;             // 256 threads, 4 elems each
    int i0 = base + t * 4;
    int s = 0;
#pragma unroll
    for (int k = 0; k < 4; ++k) { int id = i0 + k; if (id < n) s += deg[id]; }
#pragma unroll
    for (int m = 1; m <= 32; m <<= 1) s += __shfl_xor(s, m, 64);
    __shared__ int wsum[4];
    if ((t & 63) == 0) wsum[t >> 6] = s;
    __syncthreads();
    if (t == 0) part[blockIdx.x] = wsum[0] + wsum[1] + wsum[2] + wsum[3];
}

__global__ void scan_block_kernel(int* __restrict__ part, int nb) {
    __shared__ int sh[256];          // nb <= 256
    int t = threadIdx.x;
    int v = (t < nb) ? part[t] : 0;
    sh[t] = v;
    __syncthreads();
    for (int d = 1; d < 256; d <<= 1) {
        int x = (t >= d) ? sh[t - d] : 0;
        __syncthreads();
        sh[t] += x;
        __syncthreads();
    }
    if (t < nb) part[t] = sh[t] - v; // exclusive
}

__global__ void scan_final_kernel(const int* __restrict__ deg, const int* __restrict__ part,
                                  int* __restrict__ off, int n, int total) {
    int base = blockIdx.x * 1024;
    int t = threadIdx.x;
    int lane = t & 63, w = t >> 6;
    int i0 = base + t * 4;
    int v[4]; int s = 0;
#pragma unroll
    for (int k = 0; k < 4; ++k) { int id = i0 + k; v[k] = (id < n) ? deg[id] : 0; s += v[k]; }
    int incl = s;
#pragma unroll
    for (int d = 1; d < 64; d <<= 1) { int x = __shfl_up(incl, d, 64); if (lane >= d) incl += x; }
    __shared__ int wsum[4];
    if (lane == 63) wsum[w] = incl;
    __syncthreads();
    int woff = 0;
    for (int i = 0; i < w; ++i) woff += wsum[i];
    int excl = incl - s + woff + part[blockIdx.x];
#pragma unroll
    for (int k = 0; k < 4; ++k) { int id = i0 + k; if (id < n) off[id] = excl; excl += v[k]; }
    if (blockIdx.x == 0 && t == 0) off[n] = total;
}

// ---------------- CSR build: fill (KG: pack tail | type<<17) ----------------
__global__ void fill_kg_kernel(const int* __restrict__ head, const int* __restrict__ tail,
                               const int* __restrict__ etype,
                               int* __restrict__ cur, int* __restrict__ col, int E) {
    int e = blockIdx.x * blockDim.x + threadIdx.x;
    if (e >= E) return;
    int pos = atomicAdd(&cur[head[e]], 1);
    col[pos] = tail[e] | ((etype[e] - 1) << 17);   // tail < 2^17, type in [0,16)
}

__global__ void fill_ui_kernel(const int* __restrict__ uu, const int* __restrict__ ii,
                               const float* __restrict__ w,
                               int* __restrict__ cur, int* __restrict__ coli,
                               float* __restrict__ colw, int E) {
    int e = blockIdx.x * blockDim.x + threadIdx.x;
    if (e >= E) return;
    int pos = atomicAdd(&cur[uu[e]], 1);
    coli[pos] = ii[e];
    colw[pos] = w[e];
}

// ------- fused: per-entity attention agg  +  per-user weighted agg, one kernel -------
#define KG_EDGE(pw, rr) {                                                  \
        float rl = relS[(rr) * EMB + lane];                                \
        float pt = bfhi(pw), et = bflo(pw);                                \
        float prod = q * pt * rl;                                          \
        prod += __shfl_xor(prod, 1, 64);                                   \
        prod += __shfl_xor(prod, 2, 64);                                   \
        prod += __shfl_xor(prod, 4, 64);                                   \
        prod += __shfl_xor(prod, 8, 64);                                   \
        prod += __shfl_xor(prod, 16, 64);                                  \
        float ex = __expf(prod * INV_SQRT_DK);                             \
        den += ex;                                                         \
        num = fmaf(ex * rl, et, num); }

template <bool HOP1>
__global__ void agg_fused_kernel(const unsigned* __restrict__ packed,
                                 const unsigned short* __restrict__ e_bf,
                                 const float* __restrict__ rel_emb,
                                 const int* __restrict__ off_h, const int* __restrict__ col_h,
                                 const int* __restrict__ off_u, const int* __restrict__ col_i,
                                 const float* __restrict__ col_w,
                                 const float* __restrict__ e_base, float* __restrict__ e_cur,
                                 float* __restrict__ e_res, int n_ent,
                                 const float* __restrict__ u_base, float* __restrict__ u_res,
                                 int n_usr, int kgBlocks, int totalBlocks) {
    __shared__ float relS[16 * EMB];
    int bid = blockIdx.x;
    // Bresenham interleave of kg-role and ui-role blocks
    size_t lo = (size_t)bid * kgBlocks / totalBlocks;
    size_t hi = (size_t)(bid + 1) * kgBlocks / totalBlocks;
    int lane = threadIdx.x & 63;
    int wslot = threadIdx.x >> 6;

    if (hi > lo) {
        // ---------------- KG entity block ----------------
        for (int i = threadIdx.x; i < 16 * EMB; i += blockDim.x) relS[i] = rel_emb[i];
        __syncthreads();
        int wid = (int)lo * 4 + wslot;
        if (wid >= n_ent) return;
        int s = off_h[wid], e = off_h[wid + 1];
        float q = bfhi(packed[(size_t)wid * EMB + lane]);
        float num = 0.f, den = 0.f;
        int j = s;
        for (; j + 7 < e; j += 8) {
            int p0 = col_h[j],     p1 = col_h[j + 1], p2 = col_h[j + 2], p3 = col_h[j + 3];
            int p4 = col_h[j + 4], p5 = col_h[j + 5], p6 = col_h[j + 6], p7 = col_h[j + 7];
            unsigned w0 = packed[(size_t)(p0 & 131071) * EMB + lane];
            unsigned w1 = packed[(size_t)(p1 & 131071) * EMB + lane];
            unsigned w2 = packed[(size_t)(p2 & 131071) * EMB + lane];
            unsigned w3 = packed[(size_t)(p3 & 131071) * EMB + lane];
            unsigned w4 = packed[(size_t)(p4 & 131071) * EMB + lane];
            unsigned w5 = packed[(size_t)(p5 & 131071) * EMB + lane];
            unsigned w6 = packed[(size_t)(p6 & 131071) * EMB + lane];
            unsigned w7 = packed[(size_t)(p7 & 131071) * EMB + lane];
            KG_EDGE(w0, p0 >> 17);
            KG_EDGE(w1, p1 >> 17);
            KG_EDGE(w2, p2 >> 17);
            KG_EDGE(w3, p3 >> 17);
            KG_EDGE(w4, p4 >> 17);
            KG_EDGE(w5, p5 >> 17);
            KG_EDGE(w6, p6 >> 17);
            KG_EDGE(w7, p7 >> 17);
        }
        for (; j < e; ++j) {
            int p = col_h[j];
            unsigned w = packed[(size_t)(p & 131071) * EMB + lane];
            KG_EDGE(w, p >> 17);
        }
        float v = (e > s) ? num / den : 0.f;       // deferred softmax division
        float ss = v * v;
#pragma unroll
        for (int m = 1; m <= 32; m <<= 1) ss += __shfl_xor(ss, m, 64);
        float o = v / fmaxf(sqrtf(ss), 1e-12f);
        size_t ix = (size_t)wid * EMB + lane;
        if (HOP1) {
            e_cur[ix] = o;
            e_res[ix] = e_base[ix] + o;
        } else {
            e_res[ix] += o;
        }
    } else {
        // ---------------- UI user block ----------------
        int wid = (bid - (int)lo) * 4 + wslot;
        if (wid >= n_usr) return;
        int s = off_u[wid], e = off_u[wid + 1];
        float acc = 0.f;
        int j = s;
        for (; j + 3 < e; j += 4) {
            int i0 = col_i[j], i1 = col_i[j + 1], i2 = col_i[j + 2], i3 = col_i[j + 3];
            float w0 = col_w[j], w1 = col_w[j + 1], w2 = col_w[j + 2], w3 = col_w[j + 3];
            float v0 = bf2f(e_bf[(size_t)i0 * EMB + lane]);
            float v1 = bf2f(e_bf[(size_t)i1 * EMB + lane]);
            float v2 = bf2f(e_bf[(size_t)i2 * EMB + lane]);
            float v3 = bf2f(e_bf[(size_t)i3 * EMB + lane]);
            acc = fmaf(w0, v0, acc);
            acc = fmaf(w1, v1, acc);
            acc = fmaf(w2, v2, acc);
            acc = fmaf(w3, v3, acc);
        }
        for (; j < e; ++j)
            acc = fmaf(col_w[j], bf2f(e_bf[(size_t)col_i[j] * EMB + lane]), acc);
        float ss = acc * acc;
#pragma unroll
        for (int m = 1; m <= 32; m <<= 1) ss += __shfl_xor(ss, m, 64);
        float o = acc / fmaxf(sqrtf(ss), 1e-12f);
        size_t ix = (size_t)wid * EMB + lane;
        if (HOP1) u_res[ix] = u_base[ix] + o;
        else      u_res[ix] += o;
    }
}

extern "C" void kernel_launch(void* const* d_in, const int* in_sizes, int n_in,
                              void* d_out, int out_size, void* d_ws, size_t ws_size,
                              hipStream_t stream) {
    const float* user_emb   = (const float*)d_in[0];
    const float* entity_emb = (const float*)d_in[1];
    const int*   edge_index = (const int*)d_in[2];   // [2, E]
    const int*   edge_type  = (const int*)d_in[3];   // [E]
    const int*   inter_edge = (const int*)d_in[4];   // [2, EI]
    const float* inter_w    = (const float*)d_in[5]; // [EI]
    const float* W_Q        = (const float*)d_in[6]; // [64,64]
    const float* rel_emb    = (const float*)d_in[7]; // [16,64]

    const int E     = in_sizes[3];
    const int EI    = in_sizes[5];
    const int n_ent = in_sizes[1] / EMB;
    const int n_usr = in_sizes[0] / EMB;

    const int* head = edge_index;
    const int* tail = edge_index + E;
    const int* iu   = inter_edge;
    const int* ii   = inter_edge + EI;

    // ---- workspace layout ----
    char* ws = (char*)d_ws;
    unsigned* packed        = (unsigned*)ws;        ws += (size_t)n_ent * EMB * 4;
    unsigned short* e_bf    = (unsigned short*)ws;  ws += (size_t)n_ent * EMB * 2;
    float* e_cur = (float*)ws;                 ws += (size_t)n_ent * EMB * 4;
    int*   col_h = (int*)ws;                   ws += (size_t)E * 4;
    int*   col_i = (int*)ws;                   ws += (size_t)EI * 4;
    float* col_w = (float*)ws;                 ws += (size_t)EI * 4;
    int*   off_h = (int*)ws;                   ws += (size_t)(n_ent + 1) * 4;
    int*   cur_h = (int*)ws;                   ws += (size_t)n_ent * 4;
    int*   off_u = (int*)ws;                   ws += (size_t)(n_usr + 1) * 4;
    int*   cur_u = (int*)ws;                   ws += (size_t)n_usr * 4;
    int*   partH = (int*)ws;                   ws += 256 * 4;
    int*   partU = (int*)ws;                   ws += 256 * 4;

    float* e_res = (float*)d_out;
    float* u_res = e_res + (size_t)n_ent * EMB;

    const int nbH = (n_ent + 1023) / 1024;     // 98  (<=256)
    const int nbU = (n_usr + 1023) / 1024;     // 49  (<=256)

    // ---- CSR build (once; reused by both hops) ----
    hipMemsetAsync(cur_h, 0, (size_t)n_ent * 4, stream);
    hipMemsetAsync(cur_u, 0, (size_t)n_usr * 4, stream);
    hist_kernel<<<(E + 255) / 256, 256, 0, stream>>>(head, cur_h, E);
    hist_kernel<<<(EI + 255) / 256, 256, 0, stream>>>(iu, cur_u, EI);
    scan_partial_kernel<<<nbH, 256, 0, stream>>>(cur_h, partH, n_ent);
    scan_partial_kernel<<<nbU, 256, 0, stream>>>(cur_u, partU, n_usr);
    scan_block_kernel<<<1, 256, 0, stream>>>(partH, nbH);
    scan_block_kernel<<<1, 256, 0, stream>>>(partU, nbU);
    scan_final_kernel<<<nbH, 256, 0, stream>>>(cur_h, partH, off_h, n_ent, E);
    scan_final_kernel<<<nbU, 256, 0, stream>>>(cur_u, partU, off_u, n_usr, EI);
    hipMemcpyAsync(cur_h, off_h, (size_t)n_ent * 4, hipMemcpyDeviceToDevice, stream);
    hipMemcpyAsync(cur_u, off_u, (size_t)n_usr * 4, hipMemcpyDeviceToDevice, stream);
    fill_kg_kernel<<<(E + 255) / 256, 256, 0, stream>>>(head, tail, edge_type, cur_h, col_h, E);
    fill_ui_kernel<<<(EI + 255) / 256, 256, 0, stream>>>(iu, ii, inter_w, cur_u, col_i, col_w, EI);

    const int kgBlocks = (n_ent + 3) / 4;
    const int uiBlocks = (n_usr + 3) / 4;
    const int totalBlocks = kgBlocks + uiBlocks;

    // ---- hop 1 (e_in = entity_emb) ----
    proj_pack_kernel<<<kgBlocks, 256, 0, stream>>>(entity_emb, W_Q, packed, e_bf, n_ent);
    agg_fused_kernel<true><<<totalBlocks, 256, 0, stream>>>(
        packed, e_bf, rel_emb, off_h, col_h, off_u, col_i, col_w,
        entity_emb, e_cur, e_res, n_ent, user_emb, u_res, n_usr, kgBlocks, totalBlocks);

    // ---- hop 2 (e_in = e_cur) ----
    proj_pack_kernel<<<kgBlocks, 256, 0, stream>>>(e_cur, W_Q, packed, e_bf, n_ent);
    agg_fused_kernel<false><<<totalBlocks, 256, 0, stream>>>(
        packed, e_bf, rel_emb, off_h, col_h, off_u, col_i, col_w,
        nullptr, nullptr, e_res, n_ent, nullptr, u_res, n_usr, kgBlocks, totalBlocks);
}

// Round 6
// 952.866 us; speedup vs baseline: 2.4978x; 1.0438x over previous
//
#include <hip/hip_runtime.h>
#include <math.h>

#define EMB 64
static constexpr float INV_SQRT_DK = 0.17677669529663687f; // 1/sqrt(32)

__device__ inline unsigned short f2bf(float f) {
    union { float f; unsigned u; } v; v.f = f;
    unsigned r = v.u + 0x7FFF + ((v.u >> 16) & 1);   // round-to-nearest-even
    return (unsigned short)(r >> 16);
}
__device__ inline float bfhi(unsigned w) {           // high 16 bits as bf16
    union { float f; unsigned u; } v; v.u = w & 0xFFFF0000u; return v.f;
}
__device__ inline float bflo(unsigned w) {           // low 16 bits as bf16
    union { float f; unsigned u; } v; v.u = w << 16; return v.f;
}
__device__ inline float bf2f(unsigned short b) {
    union { float f; unsigned u; } v; v.u = ((unsigned)b) << 16; return v.f;
}

// ---- proj = e @ W_Q; emit packed (proj<<16|e) and e_bf gather tables ----
__global__ void proj_pack_kernel(const float* __restrict__ e, const float* __restrict__ W,
                                 unsigned* __restrict__ packed,
                                 unsigned short* __restrict__ e_bf, int n) {
    __shared__ float Wl[64 * 64];
    int t = threadIdx.x;
    for (int i = t; i < 64 * 64; i += blockDim.x) Wl[i] = W[i];
    __syncthreads();
    int lane = t & 63;
    int wavesPerBlock = blockDim.x >> 6;
    int wid = blockIdx.x * wavesPerBlock + (t >> 6);
    int nw = gridDim.x * wavesPerBlock;
    for (int r = wid; r < n; r += nw) {
        float x = e[(size_t)r * EMB + lane];
        float acc = 0.f;
#pragma unroll
        for (int k = 0; k < 64; ++k) {
            float ek = __shfl(x, k, 64);
            acc += ek * Wl[k * 64 + lane];
        }
        unsigned pb = f2bf(acc), eb = f2bf(x);
        size_t ix = (size_t)r * EMB + lane;
        packed[ix] = (pb << 16) | eb;
        e_bf[ix] = (unsigned short)eb;
    }
}

// ---------------- CSR build: fused histogram (KG heads + UI users) ----------------
__global__ void hist_both_kernel(const int* __restrict__ head, int* __restrict__ cnt_h, int E,
                                 const int* __restrict__ iu, int* __restrict__ cnt_u, int EI) {
    int e = blockIdx.x * blockDim.x + threadIdx.x;
    if (e < E) atomicAdd(&cnt_h[head[e]], 1);
    else if (e < E + EI) atomicAdd(&cnt_u[iu[e - E]], 1);
}

// ---------------- multi-block exclusive scan, H+U fused (3 phases) ----------------
__global__ void scan_partial_both(const int* __restrict__ degH, int* __restrict__ partH,
                                  int nH, int nbH,
                                  const int* __restrict__ degU, int* __restrict__ partU, int nU) {
    bool isU = (int)blockIdx.x >= nbH;
    const int* deg = isU ? degU : degH;
    int* part = isU ? partU : partH;
    int n = isU ? nU : nH;
    int b = isU ? blockIdx.x - nbH : blockIdx.x;
    int t = threadIdx.x;             // 256 threads, 4 elems each
    int i0 = b * 1024 + t * 4;
    int s = 0;
#pragma unroll
    for (int k = 0; k < 4; ++k) { int id = i0 + k; if (id < n) s += deg[id]; }
#pragma unroll
    for (int m = 1; m <= 32; m <<= 1) s += __shfl_xor(s, m, 64);
    __shared__ int wsum[4];
    if ((t & 63) == 0) wsum[t >> 6] = s;
    __syncthreads();
    if (t == 0) part[b] = wsum[0] + wsum[1] + wsum[2] + wsum[3];
}

__global__ void scan_block_both(int* __restrict__ partH, int nbH,
                                int* __restrict__ partU, int nbU) {
    __shared__ int sh[256];
    int t = threadIdx.x;
    for (int pass = 0; pass < 2; ++pass) {
        int* part = pass ? partU : partH;
        int nb = pass ? nbU : nbH;
        int v = (t < nb) ? part[t] : 0;
        sh[t] = v;
        __syncthreads();
        for (int d = 1; d < 256; d <<= 1) {
            int x = (t >= d) ? sh[t - d] : 0;
            __syncthreads();
            sh[t] += x;
            __syncthreads();
        }
        if (t < nb) part[t] = sh[t] - v; // exclusive
        __syncthreads();
    }
}

// writes both off[] and cur[] (fill cursor) — removes the D2D memcpys
__global__ void scan_final_both(const int* __restrict__ degH, const int* __restrict__ partH,
                                int* __restrict__ offH, int* __restrict__ curH,
                                int nH, int nbH, int totalH,
                                const int* __restrict__ degU, const int* __restrict__ partU,
                                int* __restrict__ offU, int* __restrict__ curU,
                                int nU, int totalU) {
    bool isU = (int)blockIdx.x >= nbH;
    const int* deg = isU ? degU : degH;
    const int* part = isU ? partU : partH;
    int* off = isU ? offU : offH;
    int* cur = isU ? curU : curH;
    int n = isU ? nU : nH;
    int total = isU ? totalU : totalH;
    int b = isU ? blockIdx.x - nbH : blockIdx.x;
    int t = threadIdx.x;
    int lane = t & 63, w = t >> 6;
    int i0 = b * 1024 + t * 4;
    int v[4]; int s = 0;
#pragma unroll
    for (int k = 0; k < 4; ++k) { int id = i0 + k; v[k] = (id < n) ? deg[id] : 0; s += v[k]; }
    int incl = s;
#pragma unroll
    for (int d = 1; d < 64; d <<= 1) { int x = __shfl_up(incl, d, 64); if (lane >= d) incl += x; }
    __shared__ int wsum[4];
    if (lane == 63) wsum[w] = incl;
    __syncthreads();
    int woff = 0;
    for (int i = 0; i < w; ++i) woff += wsum[i];
    int excl = incl - s + woff + part[b];
#pragma unroll
    for (int k = 0; k < 4; ++k) {
        int id = i0 + k;
        if (id < n) { off[id] = excl; cur[id] = excl; }
        excl += v[k];
    }
    if (b == 0 && t == 0) off[n] = total;
}

// ---------------- CSR build: fused fill ----------------
__global__ void fill_both_kernel(const int* __restrict__ head, const int* __restrict__ tail,
                                 const int* __restrict__ etype,
                                 int* __restrict__ cur_h, int* __restrict__ col_h, int E,
                                 const int* __restrict__ uu, const int* __restrict__ ii,
                                 const float* __restrict__ w,
                                 int* __restrict__ cur_u, int* __restrict__ col_i,
                                 float* __restrict__ col_w, int EI) {
    int e = blockIdx.x * blockDim.x + threadIdx.x;
    if (e < E) {
        int pos = atomicAdd(&cur_h[head[e]], 1);
        col_h[pos] = tail[e] | ((etype[e] - 1) << 17);   // tail < 2^17, type in [0,16)
    } else if (e < E + EI) {
        int k = e - E;
        int pos = atomicAdd(&cur_u[uu[k]], 1);
        col_i[pos] = ii[k];
        col_w[pos] = w[k];
    }
}

// ------- fused agg: KG = 2 dims/lane, 2 edges/wave;  UI = per-user weighted agg -------
// KG lane layout: half = lane>>5 selects edge of the pair; sub = lane&31; dims {2*sub, 2*sub+1}.
// head(dim) = dim>=32  <=>  sub>=16  (lane bit 4). 16-lane xor-reduce gives per-(edge,head) score.
#define KG_PAIR(J, P, W) {                                                  \
        int rr = (P) >> 17;                                                 \
        float rl0 = relS[rr * EMB + dd], rl1 = relS[rr * EMB + dd + 1];     \
        float pt0 = bfhi(W.x), pt1 = bfhi(W.y);                             \
        float et0 = bflo(W.x), et1 = bflo(W.y);                             \
        float prod = fmaf(q0 * rl0, pt0, q1 * rl1 * pt1);                   \
        prod += __shfl_xor(prod, 1, 64);                                    \
        prod += __shfl_xor(prod, 2, 64);                                    \
        prod += __shfl_xor(prod, 4, 64);                                    \
        prod += __shfl_xor(prod, 8, 64);                                    \
        float ex = __expf(prod * INV_SQRT_DK);                              \
        if ((J) + half >= e) ex = 0.f;                                      \
        den += ex;                                                          \
        num0 = fmaf(ex * rl0, et0, num0);                                   \
        num1 = fmaf(ex * rl1, et1, num1); }

template <bool HOP1>
__global__ void agg_fused_kernel(const unsigned* __restrict__ packed,
                                 const unsigned short* __restrict__ e_bf,
                                 const float* __restrict__ rel_emb,
                                 const int* __restrict__ off_h, const int* __restrict__ col_h,
                                 const int* __restrict__ off_u, const int* __restrict__ col_i,
                                 const float* __restrict__ col_w,
                                 const float* __restrict__ e_base, float* __restrict__ e_cur,
                                 float* __restrict__ e_res, int n_ent,
                                 const float* __restrict__ u_base, float* __restrict__ u_res,
                                 int n_usr, int kgBlocks, int totalBlocks) {
    __shared__ float relS[16 * EMB];
    int bid = blockIdx.x;
    // Bresenham interleave of kg-role and ui-role blocks
    size_t lo = (size_t)bid * kgBlocks / totalBlocks;
    size_t hi = (size_t)(bid + 1) * kgBlocks / totalBlocks;
    int lane = threadIdx.x & 63;
    int wslot = threadIdx.x >> 6;

    if (hi > lo) {
        // ---------------- KG entity block: 2 dims/lane, 2 edges/wave ----------------
        for (int i = threadIdx.x; i < 16 * EMB; i += blockDim.x) relS[i] = rel_emb[i];
        __syncthreads();
        int wid = (int)lo * 4 + wslot;
        if (wid >= n_ent) return;
        int s = off_h[wid], e = off_h[wid + 1];
        int half = lane >> 5;
        int sub  = lane & 31;
        int dd   = sub * 2;
        uint2 qw = *(const uint2*)&packed[(size_t)wid * EMB + dd];
        float q0 = bfhi(qw.x), q1 = bfhi(qw.y);
        float num0 = 0.f, num1 = 0.f, den = 0.f;
        int j = s;
        for (; j + 3 < e; j += 4) {           // 2 pairs (4 edges), no dummies possible
            int pA = col_h[j + half];
            int pB = col_h[j + 2 + half];
            uint2 wA = *(const uint2*)&packed[(size_t)(pA & 131071) * EMB + dd];
            uint2 wB = *(const uint2*)&packed[(size_t)(pB & 131071) * EMB + dd];
            KG_PAIR(j, pA, wA);
            KG_PAIR(j + 2, pB, wB);
        }
        for (; j < e; j += 2) {               // remainder pair, may have a dummy lane-half
            int jj = j + half; if (jj >= e) jj = e - 1;
            int pA = col_h[jj];
            uint2 wA = *(const uint2*)&packed[(size_t)(pA & 131071) * EMB + dd];
            KG_PAIR(j, pA, wA);
        }
        // combine the two edge-halves (once per node)
        den  += __shfl_xor(den, 32, 64);
        num0 += __shfl_xor(num0, 32, 64);
        num1 += __shfl_xor(num1, 32, 64);
        float inv = (e > s) ? 1.f / den : 0.f;   // deferred softmax division
        float v0 = num0 * inv, v1 = num1 * inv;
        float ss = fmaf(v0, v0, v1 * v1);
#pragma unroll
        for (int m = 1; m <= 16; m <<= 1) ss += __shfl_xor(ss, m, 64);
        float rn = 1.f / fmaxf(sqrtf(ss), 1e-12f);
        float o0 = v0 * rn, o1 = v1 * rn;
        if (half == 0) {
            float2* res2 = (float2*)&e_res[(size_t)wid * EMB + dd];
            if (HOP1) {
                *(float2*)&e_cur[(size_t)wid * EMB + dd] = make_float2(o0, o1);
                const float2 b = *(const float2*)&e_base[(size_t)wid * EMB + dd];
                *res2 = make_float2(b.x + o0, b.y + o1);
            } else {
                float2 rv = *res2;
                *res2 = make_float2(rv.x + o0, rv.y + o1);
            }
        }
    } else {
        // ---------------- UI user block ----------------
        int wid = (bid - (int)lo) * 4 + wslot;
        if (wid >= n_usr) return;
        int s = off_u[wid], e = off_u[wid + 1];
        float acc = 0.f;
        int j = s;
        for (; j + 3 < e; j += 4) {
            int i0 = col_i[j], i1 = col_i[j + 1], i2 = col_i[j + 2], i3 = col_i[j + 3];
            float w0 = col_w[j], w1 = col_w[j + 1], w2 = col_w[j + 2], w3 = col_w[j + 3];
            float v0 = bf2f(e_bf[(size_t)i0 * EMB + lane]);
            float v1 = bf2f(e_bf[(size_t)i1 * EMB + lane]);
            float v2 = bf2f(e_bf[(size_t)i2 * EMB + lane]);
            float v3 = bf2f(e_bf[(size_t)i3 * EMB + lane]);
            acc = fmaf(w0, v0, acc);
            acc = fmaf(w1, v1, acc);
            acc = fmaf(w2, v2, acc);
            acc = fmaf(w3, v3, acc);
        }
        for (; j < e; ++j)
            acc = fmaf(col_w[j], bf2f(e_bf[(size_t)col_i[j] * EMB + lane]), acc);
        float ss = acc * acc;
#pragma unroll
        for (int m = 1; m <= 32; m <<= 1) ss += __shfl_xor(ss, m, 64);
        float o = acc / fmaxf(sqrtf(ss), 1e-12f);
        size_t ix = (size_t)wid * EMB + lane;
        if (HOP1) u_res[ix] = u_base[ix] + o;
        else      u_res[ix] += o;
    }
}

extern "C" void kernel_launch(void* const* d_in, const int* in_sizes, int n_in,
                              void* d_out, int out_size, void* d_ws, size_t ws_size,
                              hipStream_t stream) {
    const float* user_emb   = (const float*)d_in[0];
    const float* entity_emb = (const float*)d_in[1];
    const int*   edge_index = (const int*)d_in[2];   // [2, E]
    const int*   edge_type  = (const int*)d_in[3];   // [E]
    const int*   inter_edge = (const int*)d_in[4];   // [2, EI]
    const float* inter_w    = (const float*)d_in[5]; // [EI]
    const float* W_Q        = (const float*)d_in[6]; // [64,64]
    const float* rel_emb    = (const float*)d_in[7]; // [16,64]

    const int E     = in_sizes[3];
    const int EI    = in_sizes[5];
    const int n_ent = in_sizes[1] / EMB;
    const int n_usr = in_sizes[0] / EMB;

    const int* head = edge_index;
    const int* tail = edge_index + E;
    const int* iu   = inter_edge;
    const int* ii   = inter_edge + EI;

    // ---- workspace layout ----
    char* ws = (char*)d_ws;
    unsigned* packed        = (unsigned*)ws;        ws += (size_t)n_ent * EMB * 4;
    unsigned short* e_bf    = (unsigned short*)ws;  ws += (size_t)n_ent * EMB * 2;
    float* e_cur = (float*)ws;                 ws += (size_t)n_ent * EMB * 4;
    int*   col_h = (int*)ws;                   ws += (size_t)E * 4;
    int*   col_i = (int*)ws;                   ws += (size_t)EI * 4;
    float* col_w = (float*)ws;                 ws += (size_t)EI * 4;
    int*   off_h = (int*)ws;                   ws += (size_t)(n_ent + 1) * 4;
    int*   off_u = (int*)ws;                   ws += (size_t)(n_usr + 1) * 4;
    int*   cur_h = (int*)ws;                   ws += (size_t)n_ent * 4;   // cur_h|cur_u adjacent
    int*   cur_u = (int*)ws;                   ws += (size_t)n_usr * 4;
    int*   partH = (int*)ws;                   ws += 256 * 4;
    int*   partU = (int*)ws;                   ws += 256 * 4;

    float* e_res = (float*)d_out;
    float* u_res = e_res + (size_t)n_ent * EMB;

    const int nbH = (n_ent + 1023) / 1024;     // 98  (<=256)
    const int nbU = (n_usr + 1023) / 1024;     // 49  (<=256)

    // ---- CSR build (once; reused by both hops) ----
    hipMemsetAsync(cur_h, 0, (size_t)(n_ent + n_usr) * 4, stream);
    hist_both_kernel<<<(E + EI + 255) / 256, 256, 0, stream>>>(head, cur_h, E, iu, cur_u, EI);
    scan_partial_both<<<nbH + nbU, 256, 0, stream>>>(cur_h, partH, n_ent, nbH, cur_u, partU, n_usr);
    scan_block_both<<<1, 256, 0, stream>>>(partH, nbH, partU, nbU);
    scan_final_both<<<nbH + nbU, 256, 0, stream>>>(cur_h, partH, off_h, cur_h, n_ent, nbH, E,
                                                   cur_u, partU, off_u, cur_u, n_usr, EI);
    fill_both_kernel<<<(E + EI + 255) / 256, 256, 0, stream>>>(
        head, tail, edge_type, cur_h, col_h, E, iu, ii, inter_w, cur_u, col_i, col_w, EI);

    const int kgBlocks = (n_ent + 3) / 4;
    const int uiBlocks = (n_usr + 3) / 4;
    const int totalBlocks = kgBlocks + uiBlocks;

    // ---- hop 1 (e_in = entity_emb) ----
    proj_pack_kernel<<<kgBlocks, 256, 0, stream>>>(entity_emb, W_Q, packed, e_bf, n_ent);
    agg_fused_kernel<true><<<totalBlocks, 256, 0, stream>>>(
        packed, e_bf, rel_emb, off_h, col_h, off_u, col_i, col_w,
        entity_emb, e_cur, e_res, n_ent, user_emb, u_res, n_usr, kgBlocks, totalBlocks);

    // ---- hop 2 (e_in = e_cur) ----
    proj_pack_kernel<<<kgBlocks, 256, 0, stream>>>(e_cur, W_Q, packed, e_bf, n_ent);
    agg_fused_kernel<false><<<totalBlocks, 256, 0, stream>>>(
        packed, e_bf, rel_emb, off_h, col_h, off_u, col_i, col_w,
        nullptr, nullptr, e_res, n_ent, nullptr, u_res, n_usr, kgBlocks, totalBlocks);
}

// Round 7
// 833.943 us; speedup vs baseline: 2.8540x; 1.1426x over previous
//
#include <hip/hip_runtime.h>
#include <math.h>

#define EMB 64
static constexpr float INV_SQRT_DK = 0.17677669529663687f; // 1/sqrt(32)

// fill kernel geometry: 8 partitions (XCDs) x sub-chunks, all 768 blocks co-resident (3/CU)
#define KG_FILL_BLOCKS 512   // 8 x 64
#define UI_FILL_BLOCKS 256   // 8 x 32

__device__ inline unsigned short f2bf(float f) {
    union { float f; unsigned u; } v; v.f = f;
    unsigned r = v.u + 0x7FFF + ((v.u >> 16) & 1);   // round-to-nearest-even
    return (unsigned short)(r >> 16);
}
__device__ inline float bfhi(unsigned w) {           // high 16 bits as bf16
    union { float f; unsigned u; } v; v.u = w & 0xFFFF0000u; return v.f;
}
__device__ inline float bflo(unsigned w) {           // low 16 bits as bf16
    union { float f; unsigned u; } v; v.u = w << 16; return v.f;
}
__device__ inline float bf2f(unsigned short b) {
    union { float f; unsigned u; } v; v.u = ((unsigned)b) << 16; return v.f;
}

// ---- proj = e @ W_Q; emit packed (proj<<16|e) and e_bf gather tables ----
__global__ void proj_pack_kernel(const float* __restrict__ e, const float* __restrict__ W,
                                 unsigned* __restrict__ packed,
                                 unsigned short* __restrict__ e_bf, int n) {
    __shared__ float Wl[64 * 64];
    int t = threadIdx.x;
    for (int i = t; i < 64 * 64; i += blockDim.x) Wl[i] = W[i];
    __syncthreads();
    int lane = t & 63;
    int wavesPerBlock = blockDim.x >> 6;
    int wid = blockIdx.x * wavesPerBlock + (t >> 6);
    int nw = gridDim.x * wavesPerBlock;
    for (int r = wid; r < n; r += nw) {
        float x = e[(size_t)r * EMB + lane];
        float acc = 0.f;
#pragma unroll
        for (int k = 0; k < 64; ++k) {
            float ek = __shfl(x, k, 64);
            acc += ek * Wl[k * 64 + lane];
        }
        unsigned pb = f2bf(acc), eb = f2bf(x);
        size_t ix = (size_t)r * EMB + lane;
        packed[ix] = (pb << 16) | eb;
        e_bf[ix] = (unsigned short)eb;
    }
}

// ---------------- CSR build: fused histogram (KG heads + UI users) ----------------
__global__ void hist_both_kernel(const int* __restrict__ head, int* __restrict__ cnt_h, int E,
                                 const int* __restrict__ iu, int* __restrict__ cnt_u, int EI) {
    int e = blockIdx.x * blockDim.x + threadIdx.x;
    if (e < E) atomicAdd(&cnt_h[head[e]], 1);
    else if (e < E + EI) atomicAdd(&cnt_u[iu[e - E]], 1);
}

// ---------------- multi-block exclusive scan, H+U fused (3 phases) ----------------
__global__ void scan_partial_both(const int* __restrict__ degH, int* __restrict__ partH,
                                  int nH, int nbH,
                                  const int* __restrict__ degU, int* __restrict__ partU, int nU) {
    bool isU = (int)blockIdx.x >= nbH;
    const int* deg = isU ? degU : degH;
    int* part = isU ? partU : partH;
    int n = isU ? nU : nH;
    int b = isU ? blockIdx.x - nbH : blockIdx.x;
    int t = threadIdx.x;             // 256 threads, 4 elems each
    int i0 = b * 1024 + t * 4;
    int s = 0;
#pragma unroll
    for (int k = 0; k < 4; ++k) { int id = i0 + k; if (id < n) s += deg[id]; }
#pragma unroll
    for (int m = 1; m <= 32; m <<= 1) s += __shfl_xor(s, m, 64);
    __shared__ int wsum[4];
    if ((t & 63) == 0) wsum[t >> 6] = s;
    __syncthreads();
    if (t == 0) part[b] = wsum[0] + wsum[1] + wsum[2] + wsum[3];
}

__global__ void scan_block_both(int* __restrict__ partH, int nbH,
                                int* __restrict__ partU, int nbU) {
    __shared__ int sh[256];
    int t = threadIdx.x;
    for (int pass = 0; pass < 2; ++pass) {
        int* part = pass ? partU : partH;
        int nb = pass ? nbU : nbH;
        int v = (t < nb) ? part[t] : 0;
        sh[t] = v;
        __syncthreads();
        for (int d = 1; d < 256; d <<= 1) {
            int x = (t >= d) ? sh[t - d] : 0;
            __syncthreads();
            sh[t] += x;
            __syncthreads();
        }
        if (t < nb) part[t] = sh[t] - v; // exclusive
        __syncthreads();
    }
}

// writes both off[] and cur[] (fill cursor) — removes the D2D memcpys
__global__ void scan_final_both(const int* __restrict__ degH, const int* __restrict__ partH,
                                int* __restrict__ offH, int* __restrict__ curH,
                                int nH, int nbH, int totalH,
                                const int* __restrict__ degU, const int* __restrict__ partU,
                                int* __restrict__ offU, int* __restrict__ curU,
                                int nU, int totalU) {
    bool isU = (int)blockIdx.x >= nbH;
    const int* deg = isU ? degU : degH;
    const int* part = isU ? partU : partH;
    int* off = isU ? offU : offH;
    int* cur = isU ? curU : curH;
    int n = isU ? nU : nH;
    int total = isU ? totalU : totalH;
    int b = isU ? blockIdx.x - nbH : blockIdx.x;
    int t = threadIdx.x;
    int lane = t & 63, w = t >> 6;
    int i0 = b * 1024 + t * 4;
    int v[4]; int s = 0;
#pragma unroll
    for (int k = 0; k < 4; ++k) { int id = i0 + k; v[k] = (id < n) ? deg[id] : 0; s += v[k]; }
    int incl = s;
#pragma unroll
    for (int d = 1; d < 64; d <<= 1) { int x = __shfl_up(incl, d, 64); if (lane >= d) incl += x; }
    __shared__ int wsum[4];
    if (lane == 63) wsum[w] = incl;
    __syncthreads();
    int woff = 0;
    for (int i = 0; i < w; ++i) woff += wsum[i];
    int excl = incl - s + woff + part[b];
#pragma unroll
    for (int k = 0; k < 4; ++k) {
        int id = i0 + k;
        if (id < n) { off[id] = excl; cur[id] = excl; }
        excl += v[k];
    }
    if (b == 0 && t == 0) off[n] = total;
}

// ---------------- CSR build: XCD-partitioned fill ----------------
// 768 co-resident blocks (3/CU); hardware round-robins blockIdx%8 across the 8 XCDs,
// so partition p = blockIdx&7 keeps each col region's writes inside ONE XCD's L2
// (coalesces dirty lines before writeback; round-6 showed 14x write amplification
// when all XCDs scatter into the same lines).
__global__ void __launch_bounds__(256) fill_part_kernel(
        const int* __restrict__ head, const int* __restrict__ tail,
        const int* __restrict__ etype,
        int* __restrict__ cur_h, int* __restrict__ col_h, int E, int n_ent,
        const int* __restrict__ uu, const int* __restrict__ ii,
        const float* __restrict__ w,
        int* __restrict__ cur_u, unsigned* __restrict__ col_ui, int EI, int n_usr) {
    int b = blockIdx.x;
    int p = b & 7;
    if (b < KG_FILL_BLOCKS) {
        const int nsub = KG_FILL_BLOCKS >> 3;          // 64 sub-chunks
        int sub = b >> 3;
        int chunk = (E + nsub - 1) / nsub;
        int lo = sub * chunk;
        int hiE = min(lo + chunk, E);
        int pdiv = (n_ent + 7) >> 3;
        int plo = p * pdiv;
        for (int e = lo + (int)threadIdx.x; e < hiE; e += 256) {
            int h = head[e];
            if ((unsigned)(h - plo) < (unsigned)pdiv) {
                int pos = atomicAdd(&cur_h[h], 1);
                col_h[pos] = tail[e] | ((etype[e] - 1) << 17);   // tail < 2^17, type in [0,16)
            }
        }
    } else {
        int bb = b - KG_FILL_BLOCKS;
        const int nsub = UI_FILL_BLOCKS >> 3;          // 32 sub-chunks
        int sub = bb >> 3;
        int chunk = (EI + nsub - 1) / nsub;
        int lo = sub * chunk;
        int hiE = min(lo + chunk, EI);
        int udiv = (n_usr + 7) >> 3;
        int plo = p * udiv;
        for (int e = lo + (int)threadIdx.x; e < hiE; e += 256) {
            int u = uu[e];
            if ((unsigned)(u - plo) < (unsigned)udiv) {
                int pos = atomicAdd(&cur_u[u], 1);
                // pack item (17 bits) | 15-bit fixed-point weight in [0,1)
                unsigned wq = (unsigned)(w[e] * 32767.f + 0.5f);
                col_ui[pos] = (unsigned)ii[e] | (wq << 17);
            }
        }
    }
}

// ------- fused agg: KG = 2 dims/lane, 2 edges/wave;  UI = per-user weighted agg -------
// KG lane layout: half = lane>>5 selects edge of the pair; sub = lane&31; dims {2*sub, 2*sub+1}.
// head(dim) = dim>=32  <=>  sub>=16  (lane bit 4). 16-lane xor-reduce gives per-(edge,head) score.
#define KG_PAIR(J, P, W) {                                                  \
        int rr = (P) >> 17;                                                 \
        float rl0 = relS[rr * EMB + dd], rl1 = relS[rr * EMB + dd + 1];     \
        float pt0 = bfhi(W.x), pt1 = bfhi(W.y);                             \
        float et0 = bflo(W.x), et1 = bflo(W.y);                             \
        float prod = fmaf(q0 * rl0, pt0, q1 * rl1 * pt1);                   \
        prod += __shfl_xor(prod, 1, 64);                                    \
        prod += __shfl_xor(prod, 2, 64);                                    \
        prod += __shfl_xor(prod, 4, 64);                                    \
        prod += __shfl_xor(prod, 8, 64);                                    \
        float ex = __expf(prod * INV_SQRT_DK);                              \
        if ((J) + half >= e) ex = 0.f;                                      \
        den += ex;                                                          \
        num0 = fmaf(ex * rl0, et0, num0);                                   \
        num1 = fmaf(ex * rl1, et1, num1); }

template <bool HOP1>
__global__ void agg_fused_kernel(const unsigned* __restrict__ packed,
                                 const unsigned short* __restrict__ e_bf,
                                 const float* __restrict__ rel_emb,
                                 const int* __restrict__ off_h, const int* __restrict__ col_h,
                                 const int* __restrict__ off_u,
                                 const unsigned* __restrict__ col_ui,
                                 const float* __restrict__ e_base, float* __restrict__ e_cur,
                                 float* __restrict__ e_res, int n_ent,
                                 const float* __restrict__ u_base, float* __restrict__ u_res,
                                 int n_usr, int kgBlocks, int totalBlocks) {
    __shared__ float relS[16 * EMB];
    int bid = blockIdx.x;
    // Bresenham interleave of kg-role and ui-role blocks
    size_t lo = (size_t)bid * kgBlocks / totalBlocks;
    size_t hi = (size_t)(bid + 1) * kgBlocks / totalBlocks;
    int lane = threadIdx.x & 63;
    int wslot = threadIdx.x >> 6;

    if (hi > lo) {
        // ---------------- KG entity block: 2 dims/lane, 2 edges/wave ----------------
        for (int i = threadIdx.x; i < 16 * EMB; i += blockDim.x) relS[i] = rel_emb[i];
        __syncthreads();
        int wid = (int)lo * 4 + wslot;
        if (wid >= n_ent) return;
        int s = off_h[wid], e = off_h[wid + 1];
        int half = lane >> 5;
        int sub  = lane & 31;
        int dd   = sub * 2;
        uint2 qw = *(const uint2*)&packed[(size_t)wid * EMB + dd];
        float q0 = bfhi(qw.x), q1 = bfhi(qw.y);
        float num0 = 0.f, num1 = 0.f, den = 0.f;
        int j = s;
        for (; j + 3 < e; j += 4) {           // 2 pairs (4 edges), no dummies possible
            int pA = col_h[j + half];
            int pB = col_h[j + 2 + half];
            uint2 wA = *(const uint2*)&packed[(size_t)(pA & 131071) * EMB + dd];
            uint2 wB = *(const uint2*)&packed[(size_t)(pB & 131071) * EMB + dd];
            KG_PAIR(j, pA, wA);
            KG_PAIR(j + 2, pB, wB);
        }
        for (; j < e; j += 2) {               // remainder pair, may have a dummy lane-half
            int jj = j + half; if (jj >= e) jj = e - 1;
            int pA = col_h[jj];
            uint2 wA = *(const uint2*)&packed[(size_t)(pA & 131071) * EMB + dd];
            KG_PAIR(j, pA, wA);
        }
        // combine the two edge-halves (once per node)
        den  += __shfl_xor(den, 32, 64);
        num0 += __shfl_xor(num0, 32, 64);
        num1 += __shfl_xor(num1, 32, 64);
        float inv = (e > s) ? 1.f / den : 0.f;   // deferred softmax division
        float v0 = num0 * inv, v1 = num1 * inv;
        float ss = fmaf(v0, v0, v1 * v1);
#pragma unroll
        for (int m = 1; m <= 16; m <<= 1) ss += __shfl_xor(ss, m, 64);
        float rn = 1.f / fmaxf(sqrtf(ss), 1e-12f);
        float o0 = v0 * rn, o1 = v1 * rn;
        if (half == 0) {
            float2* res2 = (float2*)&e_res[(size_t)wid * EMB + dd];
            if (HOP1) {
                *(float2*)&e_cur[(size_t)wid * EMB + dd] = make_float2(o0, o1);
                const float2 b = *(const float2*)&e_base[(size_t)wid * EMB + dd];
                *res2 = make_float2(b.x + o0, b.y + o1);
            } else {
                float2 rv = *res2;
                *res2 = make_float2(rv.x + o0, rv.y + o1);
            }
        }
    } else {
        // ---------------- UI user block ----------------
        int wid = (bid - (int)lo) * 4 + wslot;
        if (wid >= n_usr) return;
        int s = off_u[wid], e = off_u[wid + 1];
        float acc = 0.f;
        int j = s;
        for (; j + 3 < e; j += 4) {
            unsigned c0 = col_ui[j],     c1 = col_ui[j + 1];
            unsigned c2 = col_ui[j + 2], c3 = col_ui[j + 3];
            float w0 = (c0 >> 17) * (1.f / 32767.f);
            float w1 = (c1 >> 17) * (1.f / 32767.f);
            float w2 = (c2 >> 17) * (1.f / 32767.f);
            float w3 = (c3 >> 17) * (1.f / 32767.f);
            float v0 = bf2f(e_bf[(size_t)(c0 & 131071u) * EMB + lane]);
            float v1 = bf2f(e_bf[(size_t)(c1 & 131071u) * EMB + lane]);
            float v2 = bf2f(e_bf[(size_t)(c2 & 131071u) * EMB + lane]);
            float v3 = bf2f(e_bf[(size_t)(c3 & 131071u) * EMB + lane]);
            acc = fmaf(w0, v0, acc);
            acc = fmaf(w1, v1, acc);
            acc = fmaf(w2, v2, acc);
            acc = fmaf(w3, v3, acc);
        }
        for (; j < e; ++j) {
            unsigned c = col_ui[j];
            acc = fmaf((c >> 17) * (1.f / 32767.f),
                       bf2f(e_bf[(size_t)(c & 131071u) * EMB + lane]), acc);
        }
        float ss = acc * acc;
#pragma unroll
        for (int m = 1; m <= 32; m <<= 1) ss += __shfl_xor(ss, m, 64);
        float o = acc / fmaxf(sqrtf(ss), 1e-12f);
        size_t ix = (size_t)wid * EMB + lane;
        if (HOP1) u_res[ix] = u_base[ix] + o;
        else      u_res[ix] += o;
    }
}

extern "C" void kernel_launch(void* const* d_in, const int* in_sizes, int n_in,
                              void* d_out, int out_size, void* d_ws, size_t ws_size,
                              hipStream_t stream) {
    const float* user_emb   = (const float*)d_in[0];
    const float* entity_emb = (const float*)d_in[1];
    const int*   edge_index = (const int*)d_in[2];   // [2, E]
    const int*   edge_type  = (const int*)d_in[3];   // [E]
    const int*   inter_edge = (const int*)d_in[4];   // [2, EI]
    const float* inter_w    = (const float*)d_in[5]; // [EI]
    const float* W_Q        = (const float*)d_in[6]; // [64,64]
    const float* rel_emb    = (const float*)d_in[7]; // [16,64]

    const int E     = in_sizes[3];
    const int EI    = in_sizes[5];
    const int n_ent = in_sizes[1] / EMB;
    const int n_usr = in_sizes[0] / EMB;

    const int* head = edge_index;
    const int* tail = edge_index + E;
    const int* iu   = inter_edge;
    const int* ii   = inter_edge + EI;

    // ---- workspace layout ----
    char* ws = (char*)d_ws;
    unsigned* packed        = (unsigned*)ws;        ws += (size_t)n_ent * EMB * 4;
    unsigned short* e_bf    = (unsigned short*)ws;  ws += (size_t)n_ent * EMB * 2;
    float* e_cur = (float*)ws;                 ws += (size_t)n_ent * EMB * 4;
    int*      col_h  = (int*)ws;               ws += (size_t)E * 4;
    unsigned* col_ui = (unsigned*)ws;          ws += (size_t)EI * 4;
    int*   off_h = (int*)ws;                   ws += (size_t)(n_ent + 1) * 4;
    int*   off_u = (int*)ws;                   ws += (size_t)(n_usr + 1) * 4;
    int*   cur_h = (int*)ws;                   ws += (size_t)n_ent * 4;   // cur_h|cur_u adjacent
    int*   cur_u = (int*)ws;                   ws += (size_t)n_usr * 4;
    int*   partH = (int*)ws;                   ws += 256 * 4;
    int*   partU = (int*)ws;                   ws += 256 * 4;

    float* e_res = (float*)d_out;
    float* u_res = e_res + (size_t)n_ent * EMB;

    const int nbH = (n_ent + 1023) / 1024;     // 98  (<=256)
    const int nbU = (n_usr + 1023) / 1024;     // 49  (<=256)

    // ---- CSR build (once; reused by both hops) ----
    hipMemsetAsync(cur_h, 0, (size_t)(n_ent + n_usr) * 4, stream);
    hist_both_kernel<<<(E + EI + 255) / 256, 256, 0, stream>>>(head, cur_h, E, iu, cur_u, EI);
    scan_partial_both<<<nbH + nbU, 256, 0, stream>>>(cur_h, partH, n_ent, nbH, cur_u, partU, n_usr);
    scan_block_both<<<1, 256, 0, stream>>>(partH, nbH, partU, nbU);
    scan_final_both<<<nbH + nbU, 256, 0, stream>>>(cur_h, partH, off_h, cur_h, n_ent, nbH, E,
                                                   cur_u, partU, off_u, cur_u, n_usr, EI);
    fill_part_kernel<<<KG_FILL_BLOCKS + UI_FILL_BLOCKS, 256, 0, stream>>>(
        head, tail, edge_type, cur_h, col_h, E, n_ent,
        iu, ii, inter_w, cur_u, col_ui, EI, n_usr);

    const int kgBlocks = (n_ent + 3) / 4;
    const int uiBlocks = (n_usr + 3) / 4;
    const int totalBlocks = kgBlocks + uiBlocks;

    // ---- hop 1 (e_in = entity_emb) ----
    proj_pack_kernel<<<kgBlocks, 256, 0, stream>>>(entity_emb, W_Q, packed, e_bf, n_ent);
    agg_fused_kernel<true><<<totalBlocks, 256, 0, stream>>>(
        packed, e_bf, rel_emb, off_h, col_h, off_u, col_ui,
        entity_emb, e_cur, e_res, n_ent, user_emb, u_res, n_usr, kgBlocks, totalBlocks);

    // ---- hop 2 (e_in = e_cur) ----
    proj_pack_kernel<<<kgBlocks, 256, 0, stream>>>(e_cur, W_Q, packed, e_bf, n_ent);
    agg_fused_kernel<false><<<totalBlocks, 256, 0, stream>>>(
        packed, e_bf, rel_emb, off_h, col_h, off_u, col_ui,
        nullptr, nullptr, e_res, n_ent, nullptr, u_res, n_usr, kgBlocks, totalBlocks);
}